// Round 1
// baseline (604.546 us; speedup 1.0000x reference)
//
#include <hip/hip_runtime.h>
#include <math.h>

#define NG 800000

__device__ __forceinline__ float sis(float t) {
    // safe_inverse_sigmoid with LOGIT_MAX=0.99 -> clip [0.01, 0.99]
    t = fminf(fmaxf(t, 0.01f), 0.99f);
    return logf(t / (1.0f - t));
}

// Kernel 1: per-gaussian geometry, masks, anchor, tag, pool copy, reuse mask.
// Also zero-fills inst rows for inactive gaussians and (compact mode) appends
// active indices to a device list.
__global__ __launch_bounds__(256) void k_geom(
    const float* __restrict__ gp,
    const float* __restrict__ w2c,
    const float* __restrict__ ck,
    const float* __restrict__ vo,
    const float* __restrict__ ss,
    const float* __restrict__ cvr,
    float* __restrict__ oA, float* __restrict__ oT,
    float* __restrict__ oI, float* __restrict__ oP,
    float* __restrict__ oM,
    int* __restrict__ cnt, int* __restrict__ lst, int compact)
{
    int i = blockIdx.x * 256 + threadIdx.x;
    if (i >= NG) return;
    const float* g = gp + (long)i * 25;
    float v[25];
    #pragma unroll
    for (int j = 0; j < 25; ++j) v[j] = g[j];

    float R00=w2c[0],R01=w2c[1],R02=w2c[2],T0=w2c[3];
    float R10=w2c[4],R11=w2c[5],R12=w2c[6],T1=w2c[7];
    float R20=w2c[8],R21=w2c[9],R22=w2c[10],T2=w2c[11];
    float x=v[0], y=v[1], zz=v[2];
    float c0 = R00*x + R01*y + R02*zz + T0;
    float c1 = R10*x + R11*y + R12*zz + T1;
    float c2 = R20*x + R21*y + R22*zz + T2;

    bool m1 = c2 > 1e-6f;
    float zc = m1 ? c2 : 1e-6f;
    float fx=ck[0], cx=ck[2], fy=ck[4], cy=ck[5];
    float fpx = fx * c0 / zc + cx;
    float fpy = fy * c1 / zc + cy;
    // floor(fpx) >= 0  <=>  fpx >= 0 ; floor(fpx) < 640 <=> fpx < 640
    bool m2 = (fpx >= 0.f) && (fpx < 640.f) && (fpy >= 0.f) && (fpy < 480.f);
    bool mall = m1 && m2;

    float n0=vo[0]+1e-3f, n1=vo[1]+1e-3f, n2=vo[2]+1e-3f;
    float f0=vo[0]+ss[0]-1e-3f, f1=vo[1]+ss[1]-1e-3f, f2=vo[2]+ss[2]-1e-3f;
    bool gpm = (x>n0)&&(x<f0)&&(y>n1)&&(y<f1)&&(zz>n2)&&(zz<f2);
    bool mdet = mall && gpm;

    // pool_updated: copy row, set col 24 where gp_mask
    float* pr = oP + (long)i * 25;
    #pragma unroll
    for (int j = 0; j < 24; ++j) pr[j] = v[j];
    pr[24] = gpm ? 1.0f : v[24];

    float tag = (v[23] == 1.0f) ? 0.5f : 0.0f;
    if (!mdet) tag = 1.0f;

    bool gm = (c0>=cvr[0])&&(c0<=cvr[3])&&(c1>=cvr[1])&&(c1<=cvr[4])&&(c2>=cvr[2])&&(c2<=cvr[5]);
    bool reuse = gpm && gm;

    oM[i] = reuse ? 1.0f : 0.0f;
    oT[i] = reuse ? tag : 0.0f;

    float* ar = oA + (long)i * 23;
    if (reuse) {
        float tr = R00 + R11 + R22;
        float qw = sqrtf(fmaxf(tr + 1.0f, 1e-8f)) * 0.5f;
        float inv4 = 0.25f / qw;
        float qx = (R21-R12)*inv4, qy=(R02-R20)*inv4, qz=(R10-R01)*inv4;
        float p0=v[6], p1=v[7], p2=v[8], p3=v[9];
        float rw = qw*p0 - qx*p1 - qy*p2 - qz*p3;
        float rx = qw*p1 + qx*p0 + qy*p3 - qz*p2;
        float ry = qw*p2 - qx*p3 + qy*p0 + qz*p1;
        float rz = qw*p3 + qx*p2 - qy*p1 + qz*p0;
        ar[0] = sis((c0 - cvr[0]) / (cvr[3]-cvr[0]));
        ar[1] = sis((c1 - cvr[1]) / (cvr[4]-cvr[1]));
        ar[2] = sis((c2 - cvr[2]) / (cvr[5]-cvr[2]));
        ar[3] = sis(v[3]); ar[4] = sis(v[4]); ar[5] = sis(v[5]);
        ar[6]=rw; ar[7]=rx; ar[8]=ry; ar[9]=rz;
        ar[10] = sis(v[10]);
        #pragma unroll
        for (int j = 0; j < 12; ++j) ar[11+j] = v[11+j];
        if (compact) {
            int t = atomicAdd(cnt, 1);
            lst[t] = i;
        }
    } else {
        #pragma unroll
        for (int j = 0; j < 23; ++j) ar[j] = 0.0f;
        float4* ir = (float4*)(oI + (long)i * 96);
        float4 z4 = make_float4(0.f, 0.f, 0.f, 0.f);
        #pragma unroll
        for (int k = 0; k < 24; ++k) ir[k] = z4;
    }
}

// Kernel 2: depth MLP (2->64->128->96) + anchor @ W_inst for active gaussians.
__global__ __launch_bounds__(256) void k_mlp(
    const float* __restrict__ gp,
    const float* __restrict__ zbuf,
    const float* __restrict__ w2c,
    const float* __restrict__ ck,
    const float* __restrict__ W1, const float* __restrict__ b1,
    const float* __restrict__ W2, const float* __restrict__ b2,
    const float* __restrict__ W3, const float* __restrict__ b3,
    const float* __restrict__ Wi, const float* __restrict__ bi,
    const float* __restrict__ anc,
    float* __restrict__ oI,
    const int* __restrict__ cnt, const int* __restrict__ lst,
    const float* __restrict__ msk, int compact)
{
    // Stage W2 transposed (columns become contiguous): sW2T[j][i2], 32 KB.
    __shared__ float sW2T[128 * 64];
    for (int idx = threadIdx.x; idx < 64 * 128; idx += 256) {
        int r = idx >> 7;       // row of W2 (0..63)
        int c = idx & 127;      // col of W2 (0..127)
        sW2T[c * 64 + r] = W2[idx];
    }
    __syncthreads();

    int t = blockIdx.x * 256 + threadIdx.x;
    int i;
    if (compact) {
        int n = *cnt;
        if (t >= n) return;
        i = lst[t];
    } else {
        if (t >= NG) return;
        if (msk[t] == 0.0f) return;
        i = t;
    }

    // Recompute df = [z[iy,ix], depth_real]
    const float* g = gp + (long)i * 25;
    float x = g[0], y = g[1], zz = g[2];
    float c0 = w2c[0]*x + w2c[1]*y + w2c[2]*zz + w2c[3];
    float c1 = w2c[4]*x + w2c[5]*y + w2c[6]*zz + w2c[7];
    float c2 = w2c[8]*x + w2c[9]*y + w2c[10]*zz + w2c[11];
    float czs = (fabsf(c2) < 1e-6f) ? 1e-6f : c2;
    float px = ck[0]*c0/czs + ck[2];
    float py = ck[4]*c1/czs + ck[5];
    float fix = fminf(fmaxf(px, 0.f), 639.f);
    float fiy = fminf(fmaxf(py, 0.f), 479.f);
    int ix = (int)fix, iy = (int)fiy;
    float d0 = zbuf[iy * 640 + ix];
    float d1 = c2;

    // h1 = relu(df @ W1 + b1)  (64)
    float h1[64];
    #pragma unroll
    for (int j = 0; j < 64; ++j)
        h1[j] = fmaxf(d0 * W1[j] + d1 * W1[64 + j] + b1[j], 0.0f);

    // acc starts at b3 + b_inst
    float acc[96];
    #pragma unroll
    for (int k = 0; k < 96; ++k) acc[k] = b3[k] + bi[k];

    // h2_j = relu(h1 . W2[:,j] + b2[j]); acc += h2_j * W3[j,:]
    for (int j = 0; j < 128; ++j) {
        const float* col = &sW2T[j * 64];
        float s0 = 0.f, s1 = 0.f, s2 = 0.f, s3 = 0.f;
        #pragma unroll
        for (int i2 = 0; i2 < 64; i2 += 4) {
            s0 += h1[i2]     * col[i2];
            s1 += h1[i2 + 1] * col[i2 + 1];
            s2 += h1[i2 + 2] * col[i2 + 2];
            s3 += h1[i2 + 3] * col[i2 + 3];
        }
        float s = fmaxf(b2[j] + ((s0 + s1) + (s2 + s3)), 0.0f);
        const float* w3r = W3 + j * 96;
        #pragma unroll
        for (int k = 0; k < 96; ++k) acc[k] += s * w3r[k];
    }

    // acc += anchor @ W_inst
    const float* ar = anc + (long)i * 23;
    #pragma unroll
    for (int c = 0; c < 23; ++c) {
        float av = ar[c];
        const float* wir = Wi + c * 96;
        #pragma unroll
        for (int k = 0; k < 96; ++k) acc[k] += av * wir[k];
    }

    float4* dst = (float4*)(oI + (long)i * 96);
    #pragma unroll
    for (int k = 0; k < 24; ++k)
        dst[k] = make_float4(acc[4*k], acc[4*k+1], acc[4*k+2], acc[4*k+3]);
}

extern "C" void kernel_launch(void* const* d_in, const int* in_sizes, int n_in,
                              void* d_out, int out_size, void* d_ws, size_t ws_size,
                              hipStream_t stream)
{
    const float* gp  = (const float*)d_in[0];
    // d_in[1] = instance_feature_pool: unused by the reference
    const float* zb  = (const float*)d_in[2];
    const float* w2c = (const float*)d_in[3];
    const float* ck  = (const float*)d_in[4];
    const float* vo  = (const float*)d_in[5];
    const float* ss  = (const float*)d_in[6];
    const float* cvr = (const float*)d_in[7];
    const float* Wi  = (const float*)d_in[8];
    const float* bi  = (const float*)d_in[9];
    const float* W1  = (const float*)d_in[10];
    const float* b1  = (const float*)d_in[11];
    const float* W2  = (const float*)d_in[12];
    const float* b2  = (const float*)d_in[13];
    const float* W3  = (const float*)d_in[14];
    const float* b3  = (const float*)d_in[15];

    float* out = (float*)d_out;
    const long N = NG;
    float* oA = out;               // (N,23)
    float* oT = out + 23L * N;     // (N,)
    float* oI = out + 24L * N;     // (N,96)
    float* oP = out + 120L * N;    // (N,25)
    float* oM = out + 145L * N;    // (N,)

    int compact = (ws_size >= (size_t)(16 + 4 * (size_t)NG)) ? 1 : 0;
    int* cnt = (int*)d_ws;
    int* lst = (int*)d_ws + 4;     // 16-byte offset

    if (compact) hipMemsetAsync(d_ws, 0, 16, stream);

    int blocks = (NG + 255) / 256;
    k_geom<<<blocks, 256, 0, stream>>>(gp, w2c, ck, vo, ss, cvr,
                                       oA, oT, oI, oP, oM, cnt, lst, compact);
    k_mlp<<<blocks, 256, 0, stream>>>(gp, zb, w2c, ck, W1, b1, W2, b2, W3, b3,
                                      Wi, bi, oA, oI, cnt, lst, oM, compact);
}